// Round 5
// baseline (1085.514 us; speedup 1.0000x reference)
//
#include <hip/hip_runtime.h>
#include <hip/hip_bf16.h>
#include <hip/hip_cooperative_groups.h>

namespace cg = cooperative_groups;

// Problem constants (fixed by reference)
static constexpr int Nn  = 8192;     // nodes
static constexpr int Hh  = 4;        // heads
static constexpr int Ee  = 131072;   // edges
static constexpr int DK  = 16;       // per-head feature dim
static constexpr int TBL = 1 << 19;  // hash table slots (load ~0.5)
static constexpr int TBLMASK = TBL - 1;
static constexpr unsigned KEYMASK = (1u << 26) - 1;   // key = (u<<13)|v, 26 bits
static constexpr int XLEN = Hh * Nn * DK;  // 524288 floats
// State layout is [hd][m][k] flat = hd*131072 + m*16 + k — EXACTLY the flat
// order of h.reshape(H,N,16) and of result.reshape(N,64). Verified in rounds 2/4.

// ---------------------------------------------------------------------------
// Kernel 1: insert all 2E directed entries; slot holds packed ((t+1)<<26)|key.
// Winner per (u,v) = max combined t (numpy last-write-wins scatter order:
//   t < E : (src,dst) first scatter; t >= E : (dst,src) second scatter).
// COUNT FUSED: the thread whose CAS claims the empty slot counts the unique
// (u,v) pair for row u; later rank-updates don't change the count.
__global__ void insert_kernel(const int* __restrict__ src, const int* __restrict__ dst,
                              unsigned long long* __restrict__ tbl,
                              int* __restrict__ row_cnt) {
    int t = blockIdx.x * blockDim.x + threadIdx.x;
    if (t >= 2 * Ee) return;
    int u, v;
    if (t < Ee) { u = src[t]; v = dst[t]; }
    else        { u = dst[t - Ee]; v = src[t - Ee]; }
    unsigned key = ((unsigned)u << 13) | (unsigned)v;   // N = 2^13
    unsigned long long want = (((unsigned long long)(t + 1)) << 26) | key;
    unsigned idx = ((key * 2654435761u) >> 6) & TBLMASK;
    while (true) {
        unsigned long long cur = tbl[idx];              // racy peek; truth via CAS
        if (cur == 0ull) {
            unsigned long long old = atomicCAS(&tbl[idx], 0ull, want);
            if (old == 0ull) { atomicAdd(&row_cnt[u], 1); return; }
            cur = old;
        }
        if ((unsigned)(cur & KEYMASK) == key) {
            while (cur < want) {                        // rank-max update
                unsigned long long old = atomicCAS(&tbl[idx], cur, want);
                if (old == cur) break;
                cur = old;
            }
            return;
        }
        idx = (idx + 1) & TBLMASK;                      // probe next slot
    }
}

// ---------------------------------------------------------------------------
// Kernel 2: single-block exclusive scan of row counts -> row_start[0..N]
__global__ void scan_kernel(const int* __restrict__ row_cnt, int* __restrict__ row_start) {
    __shared__ int sums[1024];
    int t = threadIdx.x;
    int base = t * 8;
    int local[8];
    int s = 0;
#pragma unroll
    for (int i = 0; i < 8; i++) { local[i] = s; s += row_cnt[base + i]; }
    sums[t] = s;
    __syncthreads();
    for (int off = 1; off < 1024; off <<= 1) {
        int v = 0;
        if (t >= off) v = sums[t - off];
        __syncthreads();
        if (t >= off) sums[t] += v;
        __syncthreads();
    }
    int prefix = (t == 0) ? 0 : sums[t - 1];
#pragma unroll
    for (int i = 0; i < 8; i++) row_start[base + i] = prefix + local[i];
    if (t == 1023) row_start[Nn] = sums[1023];
}

// ---------------------------------------------------------------------------
// Kernel 3: fill CSR (col,edge) packed int2 (bump-allocate within row)
__global__ void fill_kernel(const unsigned long long* __restrict__ tbl,
                            const int* __restrict__ row_start, int* __restrict__ row_fill,
                            int2* __restrict__ csr_ce) {
    int i = blockIdx.x * blockDim.x + threadIdx.x;
    if (i >= TBL) return;
    unsigned long long cur = tbl[i];
    if (cur == 0ull) return;
    unsigned key = (unsigned)(cur & KEYMASK);
    int u = (int)(key >> 13), v = (int)(key & (Nn - 1));
    int t = (int)(cur >> 26) - 1;
    int edge = (t >= Ee) ? (t - Ee) : t;
    int slot = row_start[u] + atomicAdd(&row_fill[u], 1);
    csr_ce[slot] = make_int2(v, edge);
}

// ---------------------------------------------------------------------------
// Kernel 4 (cooperative): rowsum+normalize, then all 6 Taylor sweeps.
// One wave per 2 rows (4096 waves = 1024 blocks x 256 thr = 4 blocks/CU,
// co-resident per __launch_bounds__(256,4)). Lane = (hd,k).
// res for each owned row lives in a REGISTER across all sweeps (no res buffer).
// x/y ping-pong through bufA/bufB with grid.sync() between sweeps.
__global__ void __launch_bounds__(256, 4)
diffuse_kernel(const int* __restrict__ row_start, const int2* __restrict__ csr_ce,
               float* __restrict__ val4, const float* __restrict__ e,
               const float* __restrict__ h, float* __restrict__ bufA,
               float* __restrict__ bufB, float* __restrict__ out) {
    cg::grid_group grid = cg::this_grid();
    int wave = blockIdx.x * (blockDim.x >> 6) + (threadIdx.x >> 6);  // 0..4095
    int lane = threadIdx.x & 63;
    int hd = lane >> 4, k = lane & 15;

    // ---- phase 0: per-row rowsum (shfl reduce) + normalized val4 ----
    for (int rr = 0; rr < 2; rr++) {
        int u = wave + rr * 4096;
        int s = row_start[u], send = row_start[u + 1];
        float s0 = 0.f, s1 = 0.f, s2 = 0.f, s3 = 0.f;
        for (int p = s + lane; p < send; p += 64) {
            int edge = csr_ce[p].y;
            s0 += e[0 * Ee + edge];
            s1 += e[1 * Ee + edge];
            s2 += e[2 * Ee + edge];
            s3 += e[3 * Ee + edge];
        }
#pragma unroll
        for (int off = 32; off > 0; off >>= 1) {
            s0 += __shfl_xor(s0, off, 64);
            s1 += __shfl_xor(s1, off, 64);
            s2 += __shfl_xor(s2, off, 64);
            s3 += __shfl_xor(s3, off, 64);
        }
        float i0 = 1.f / s0, i1 = 1.f / s1, i2 = 1.f / s2, i3 = 1.f / s3;
        for (int p = s + lane; p < send; p += 64) {
            int edge = csr_ce[p].y;
            val4[4 * p + 0] = e[0 * Ee + edge] * i0;
            val4[4 * p + 1] = e[1 * Ee + edge] * i1;
            val4[4 * p + 2] = e[2 * Ee + edge] * i2;
            val4[4 * p + 3] = e[3 * Ee + edge] * i3;
        }
    }
    grid.sync();

    // ---- phases 1..6: Taylor sweeps, res in registers ----
    int u0 = wave, u1 = wave + 4096;
    int s0r = row_start[u0], e0r = row_start[u0 + 1];
    int s1r = row_start[u1], e1r = row_start[u1 + 1];
    int oi0 = (hd * Nn + u0) * DK + k;
    int oi1 = (hd * Nn + u1) * DK + k;
    float res0 = h[oi0];
    float res1 = h[oi1];
    const float invf[6] = {1.f, 0.5f, 1.f / 6.f, 1.f / 24.f, 1.f / 120.f, 1.f / 720.f};
    const float* x = h;
    for (int it = 0; it < 6; it++) {
        const float* xh = x + hd * (Nn * DK) + k;
        float acc0 = 0.f, acc1 = 0.f;
        for (int p = s0r; p < e0r; p++) {
            int2 ce = csr_ce[p];                 // wave-uniform 8B
            acc0 += val4[4 * p + hd] * xh[ce.x * DK];
        }
        for (int p = s1r; p < e1r; p++) {
            int2 ce = csr_ce[p];
            acc1 += val4[4 * p + hd] * xh[ce.x * DK];
        }
        res0 += acc0 * invf[it];
        res1 += acc1 * invf[it];
        if (it < 5) {
            float* y = (it & 1) ? bufB : bufA;
            y[oi0] = acc0;
            y[oi1] = acc1;
            grid.sync();                         // publish y before next sweep reads
            x = y;
        }
    }
    out[oi0] = res0;
    out[oi1] = res1;
}

// ---------------------------------------------------------------------------
extern "C" void kernel_launch(void* const* d_in, const int* in_sizes, int n_in,
                              void* d_out, int out_size, void* d_ws, size_t ws_size,
                              hipStream_t stream) {
    const float* h = (const float*)d_in[0];
    const float* e = (const float*)d_in[1];
    const int* src = (const int*)d_in[2];
    const int* dst = (const int*)d_in[3];
    float* out = (float*)d_out;

    // Workspace carve-up (~14.5 MB)
    char* ws = (char*)d_ws;
    size_t off = 0;
    auto alloc = [&](size_t bytes) -> void* {
        void* p = ws + off;
        off = (off + bytes + 255) & ~(size_t)255;
        return p;
    };
    unsigned long long* tbl = (unsigned long long*)alloc((size_t)TBL * 8);
    int*   cnt2      = (int*)  alloc((size_t)2 * Nn * 4);  // [row_cnt | row_fill] contiguous
    int*   row_cnt   = cnt2;
    int*   row_fill  = cnt2 + Nn;
    int*   row_start = (int*)  alloc((size_t)(Nn + 1) * 4);
    int2*  csr_ce    = (int2*) alloc((size_t)2 * Ee * 8);
    float* val4      = (float*)alloc((size_t)4 * 2 * Ee * 4);
    float* bufA      = (float*)alloc((size_t)XLEN * 4);
    float* bufB      = (float*)alloc((size_t)XLEN * 4);

    const int tpb = 256;

    hipMemsetAsync(tbl, 0, (size_t)TBL * 8, stream);
    hipMemsetAsync(cnt2, 0, (size_t)2 * Nn * 4, stream);
    insert_kernel<<<(2 * Ee) / tpb, tpb, 0, stream>>>(src, dst, tbl, row_cnt);
    scan_kernel<<<1, 1024, 0, stream>>>(row_cnt, row_start);
    fill_kernel<<<TBL / tpb, tpb, 0, stream>>>(tbl, row_start, row_fill, csr_ce);

    void* args[] = {(void*)&row_start, (void*)&csr_ce, (void*)&val4, (void*)&e,
                    (void*)&h, (void*)&bufA, (void*)&bufB, (void*)&out};
    hipLaunchCooperativeKernel((void*)diffuse_kernel, dim3(1024), dim3(tpb), args, 0, stream);
}

// Round 6
// 209.957 us; speedup vs baseline: 5.1702x; 5.1702x over previous
//
#include <hip/hip_runtime.h>
#include <hip/hip_bf16.h>

// Problem constants (fixed by reference)
static constexpr int Nn  = 8192;     // nodes
static constexpr int Hh  = 4;        // heads
static constexpr int Ee  = 131072;   // edges
static constexpr int DK  = 16;       // per-head feature dim
static constexpr int CAP = 128;      // per-row bucket capacity; deg ~ Poisson(32),
                                     // P(>=128) ~ 1e-40 — guarded anyway
static constexpr int XLEN = Hh * Nn * DK;  // 524288 floats
// State layout is [hd][m][k] flat = hd*131072 + m*16 + k — EXACTLY the flat
// order of h.reshape(H,N,16) and of result.reshape(N,64). Verified rounds 2/4.
// NOTE (round 5 post-mortem): do NOT fuse sweeps with cg::grid_sync — each sync
// costs ~115us on gfx950 (cross-XCD L2 flush + 1024-block spin). Kernel
// boundaries are the cheap grid barrier here.

// ---------------------------------------------------------------------------
// Kernel 1: scatter all 2E directed entries into per-row buckets.
// Combined rank t reproduces numpy sequential last-write-wins order:
//   t < E : (src,dst) first scatter; t >= E : (dst,src) second scatter.
__global__ void scatter_kernel(const int* __restrict__ src, const int* __restrict__ dst,
                               int* __restrict__ cnt, int2* __restrict__ bucket) {
    int t = blockIdx.x * blockDim.x + threadIdx.x;
    if (t >= 2 * Ee) return;
    int u, v;
    if (t < Ee) { u = src[t]; v = dst[t]; }
    else        { u = dst[t - Ee]; v = src[t - Ee]; }
    int pos = atomicAdd(&cnt[u], 1);
    if (pos < CAP) bucket[u * CAP + pos] = make_int2(v, t);
}

// ---------------------------------------------------------------------------
// Kernel 2: per-row dedup (last-write-wins by max rank) + rowsum + normalize.
// One wave per row. Entries -> LDS; survivor = no other entry with same col
// and larger rank; ballot-compact; 4-head rowsum via shfl-reduce; write
// packed cols + val4 in bucket layout.
__global__ void __launch_bounds__(256)
dedup_kernel(const int* __restrict__ cnt, const int2* __restrict__ bucket,
             const float* __restrict__ e, int* __restrict__ cnt2,
             int* __restrict__ cols, float* __restrict__ val4) {
    __shared__ int lv[4][CAP];
    __shared__ int lt[4][CAP];
    int w = threadIdx.x >> 6;
    int lane = threadIdx.x & 63;
    int u = blockIdx.x * 4 + w;
    int d = cnt[u]; if (d > CAP) d = CAP;

    for (int i = lane; i < d; i += 64) {
        int2 ce = bucket[u * CAP + i];
        lv[w][i] = ce.x; lt[w][i] = ce.y;
    }
    __syncthreads();

    // survival + per-head partial rowsums (each lane owns entries lane, lane+64)
    bool  surv[2] = {false, false};
    int   vv[2], eidx[2];
    float ev[2][4];
    float s0 = 0.f, s1 = 0.f, s2 = 0.f, s3 = 0.f;
#pragma unroll
    for (int r = 0; r < 2; r++) {
        int i = lane + 64 * r;
        if (i < d) {
            int vi = lv[w][i], ti = lt[w][i];
            bool alive = true;
            for (int j = 0; j < d; j++)
                if (lv[w][j] == vi && lt[w][j] > ti) { alive = false; break; }
            surv[r] = alive;
            vv[r] = vi;
            eidx[r] = (ti >= Ee) ? (ti - Ee) : ti;
            if (alive) {
                ev[r][0] = e[0 * Ee + eidx[r]];
                ev[r][1] = e[1 * Ee + eidx[r]];
                ev[r][2] = e[2 * Ee + eidx[r]];
                ev[r][3] = e[3 * Ee + eidx[r]];
                s0 += ev[r][0]; s1 += ev[r][1]; s2 += ev[r][2]; s3 += ev[r][3];
            }
        }
    }
#pragma unroll
    for (int off = 32; off > 0; off >>= 1) {
        s0 += __shfl_xor(s0, off, 64);
        s1 += __shfl_xor(s1, off, 64);
        s2 += __shfl_xor(s2, off, 64);
        s3 += __shfl_xor(s3, off, 64);
    }
    float i0 = 1.f / s0, i1 = 1.f / s1, i2 = 1.f / s2, i3 = 1.f / s3;

    // ballot-compact survivors to packed positions
    unsigned long long m0 = __ballot(surv[0]);
    unsigned long long m1 = __ballot(surv[1]);
    unsigned long long below = ((unsigned long long)1 << lane) - 1;
    int base1 = __popcll(m0);
    int pos[2];
    pos[0] = __popcll(m0 & below);
    pos[1] = base1 + __popcll(m1 & below);
    int total = base1 + __popcll(m1);
#pragma unroll
    for (int r = 0; r < 2; r++) {
        if (surv[r]) {
            int q = u * CAP + pos[r];
            cols[q] = vv[r];
            val4[4 * q + 0] = ev[r][0] * i0;
            val4[4 * q + 1] = ev[r][1] * i1;
            val4[4 * q + 2] = ev[r][2] * i2;
            val4[4 * q + 3] = ev[r][3] * i3;
        }
    }
    if (lane == 0) cnt2[u] = total;
}

// ---------------------------------------------------------------------------
// Kernel 3: one Horner sweep.  xn = s_k * (a_norm @ x) + c_k * h
// One wave per row u; lane = (hd,k).  Bucket CSR layout, no row_start needed.
__global__ void __launch_bounds__(256)
spmv_kernel(const int* __restrict__ cnt2, const int* __restrict__ cols,
            const float* __restrict__ val4, const float* __restrict__ x,
            const float* __restrict__ h, float* __restrict__ xn,
            float s_k, float c_k) {
    int wave = blockIdx.x * (blockDim.x >> 6) + (threadIdx.x >> 6);
    int lane = threadIdx.x & 63;
    int hd = lane >> 4, k = lane & 15;
    int u = wave;
    int d = cnt2[u];
    const float* xh = x + hd * (Nn * DK) + k;
    int base = u * CAP;
    float acc = 0.f;
    for (int p = base; p < base + d; p++) {
        acc += val4[4 * p + hd] * xh[cols[p] * DK];   // 16B/wave coef + 4x64B gather
    }
    int oi = (hd * Nn + u) * DK + k;
    xn[oi] = s_k * acc + c_k * h[oi];
}

// ---------------------------------------------------------------------------
extern "C" void kernel_launch(void* const* d_in, const int* in_sizes, int n_in,
                              void* d_out, int out_size, void* d_ws, size_t ws_size,
                              hipStream_t stream) {
    const float* h = (const float*)d_in[0];
    const float* e = (const float*)d_in[1];
    const int* src = (const int*)d_in[2];
    const int* dst = (const int*)d_in[3];
    float* out = (float*)d_out;

    // Workspace carve-up (~33 MB)
    char* ws = (char*)d_ws;
    size_t off = 0;
    auto alloc = [&](size_t bytes) -> void* {
        void* p = ws + off;
        off = (off + bytes + 255) & ~(size_t)255;
        return p;
    };
    int*   cnts   = (int*)  alloc((size_t)2 * Nn * 4);        // [cnt | cnt2]
    int*   cnt    = cnts;
    int*   cnt2   = cnts + Nn;
    int2*  bucket = (int2*) alloc((size_t)Nn * CAP * 8);      // 8 MB
    int*   cols   = (int*)  alloc((size_t)Nn * CAP * 4);      // 4 MB
    float* val4   = (float*)alloc((size_t)Nn * CAP * 4 * 4);  // 16 MB
    float* bufA   = (float*)alloc((size_t)XLEN * 4);          // 2 MB
    float* bufB   = (float*)alloc((size_t)XLEN * 4);          // 2 MB

    const int tpb = 256;

    hipMemsetAsync(cnts, 0, (size_t)2 * Nn * 4, stream);
    scatter_kernel<<<(2 * Ee) / tpb, tpb, 0, stream>>>(src, dst, cnt, bucket);
    dedup_kernel<<<Nn / 4, tpb, 0, stream>>>(cnt, bucket, e, cnt2, cols, val4);

    // Horner: r = h/720; r = a r + h/120; ... ; r = a r + h  (x2)
    // sweep 1 folds the initial 1/720 into s_1; x input is h itself.
    const float s_k[6] = {1.f / 720.f, 1.f, 1.f, 1.f, 1.f, 1.f};
    const float c_k[6] = {1.f / 120.f, 1.f / 24.f, 1.f / 6.f, 0.5f, 1.f, 1.f};
    const float* xp = h;
    float* bufs[2] = {bufA, bufB};
    for (int i = 0; i < 6; i++) {
        float* xn = (i == 5) ? out : bufs[i & 1];
        spmv_kernel<<<Nn / 4, tpb, 0, stream>>>(cnt2, cols, val4, xp, h, xn, s_k[i], c_k[i]);
        xp = xn;
    }
}